// Round 15
// baseline (273.811 us; speedup 1.0000x reference)
//
#include <hip/hip_runtime.h>

// Round 30: T15-style intra-wave A/B pipeline in the flash super-tile.
// Reorder tile processing to QK_A; QK_B; SM_A+PV_A; SM_B+PV_B - QK_B's
// MFMA latency hides under SM_A's VALU chain, removing one full MFMA-wait
// stall per super-tile. Identical math & barrier schedule (pure reorder;
// m/l updates still A-then-B). Costs ~16 VGPR (both sa tiles live).
// Everything else verbatim R14 (verified 232.6us).

#define B_  2
#define L_  4096
#define D_  512
#define H_  8
#define BH_ 16
#define M_  8192

typedef __attribute__((ext_vector_type(8)))  short short8;   // 8 bf16
typedef __attribute__((ext_vector_type(4)))  float f32x4;
typedef __attribute__((ext_vector_type(16))) float f32x16;
typedef unsigned short u16;

#if __has_builtin(__builtin_amdgcn_exp2f)
#define EX2(x) __builtin_amdgcn_exp2f(x)
#else
#define EX2(x) exp2f(x)
#endif

static __device__ __forceinline__ u16 f2b(float f) {
    union { float f; unsigned i; } x; x.f = f;
    unsigned r = x.i + 0x7fff + ((x.i >> 16) & 1);   // RNE
    return (u16)(r >> 16);
}

static __device__ __forceinline__ unsigned cvt_pk_bf16(float lo, float hi) {
    unsigned r;
    asm("v_cvt_pk_bf16_f32 %0, %1, %2" : "=v"(r) : "v"(lo), "v"(hi));
    return r;
}

static __device__ __forceinline__ uint4 pk8(const float4& a, const float4& b) {
    uint4 o;
    o.x = cvt_pk_bf16(a.x, a.y);
    o.y = cvt_pk_bf16(a.z, a.w);
    o.z = cvt_pk_bf16(b.x, b.y);
    o.w = cvt_pk_bf16(b.z, b.w);
    return o;
}

static __device__ __forceinline__ void stage8f(u16* dst, const float* s) {
    const float4 a = *(const float4*)s;
    const float4 b = *(const float4*)(s + 4);
    *(uint4*)dst = pk8(a, b);
}

static __device__ __forceinline__ short8 mk8(unsigned a, unsigned b,
                                             unsigned c, unsigned d) {
    union { unsigned u[4]; short8 s; } x;
    x.u[0] = a; x.u[1] = b; x.u[2] = c; x.u[3] = d;
    return x.s;
}

// ---------------------------------------------------------------------------
// Prep: fp32 -> bf16 one-shot conversion (verbatim R14).
// ---------------------------------------------------------------------------
__global__ __launch_bounds__(256) void prep_kernel(
    const float* __restrict__ x,
    const float* __restrict__ Wq, const float* __restrict__ Wk,
    const float* __restrict__ Wv, const float* __restrict__ Wo,
    u16* __restrict__ xbf, u16* __restrict__ wbf, u16* __restrict__ wobf)
{
    const size_t NX = (size_t)B_ * L_ * D_;
    const size_t NW = (size_t)D_ * D_;
    const size_t i8 = ((size_t)blockIdx.x * 256 + threadIdx.x) * 8;
    const float* s; u16* d;
    if (i8 < NX) { s = x + i8; d = xbf + i8; }
    else {
        const size_t j = i8 - NX;
        if      (j <     NW) { s = Wq + j;          d = wbf + j; }
        else if (j < 2 * NW) { s = Wk + (j - NW);   d = wbf + j; }
        else if (j < 3 * NW) { s = Wv + (j - 2*NW); d = wbf + j; }
        else if (j < 4 * NW) {
            if (!wobf) return;
            s = Wo + (j - 3*NW); d = wobf + (j - 3*NW);
        } else return;
    }
    *(uint4*)d = pk8(*(const float4*)s, *(const float4*)(s + 4));
}

// ---------------------------------------------------------------------------
// Fused K+V projection, K-chunk 64 (verbatim R14).
// ---------------------------------------------------------------------------
template<bool BF>
__global__ __launch_bounds__(256) void kvproj_kernel(
    const float* __restrict__ x, const u16* __restrict__ xbf,
    const float* __restrict__ Wk, const float* __restrict__ bk,
    const float* __restrict__ Wv, const float* __restrict__ bv,
    const u16* __restrict__ wbf,
    u16* __restrict__ Kws, u16* __restrict__ Vws, int bh0)
{
    __shared__ __align__(16) unsigned char sm[27648];
    u16 (*As)[72]  = (u16(*)[72])sm;
    u16 (*Bks)[72] = (u16(*)[72])(sm + 9216);
    u16 (*Bvs)[72] = (u16(*)[72])(sm + 18432);
    u16 (*Ts)[73]  = (u16(*)[73])sm;

    const int t    = threadIdx.x;
    const int wid  = t >> 6, lane = t & 63;
    const int m15  = lane & 15, quad = lane >> 4;
    const int wm   = wid >> 1, wn = wid & 1;

    const int bh = bh0 + blockIdx.x;
    const int b  = bh >> 3, h = bh & 7;
    const int l0 = blockIdx.y * 64;

    const int r0   = t >> 3;
    const int scol = (t & 7) * 8;

    const size_t xo0 = ((size_t)b * L_ + l0 + r0) * 512 + scol;
    const size_t xo1 = xo0 + (size_t)32 * 512;
    const size_t wo0 = (size_t)(h * 64 + r0) * 512 + scol;
    const size_t wo1 = wo0 + (size_t)32 * 512;
    const u16* wkbf = wbf + 262144;
    const u16* wvbf = wbf + 2 * 262144;

    auto ldg = [&](const float* pf, const u16* pb, size_t off, int k) -> uint4 {
        if constexpr (BF) return *(const uint4*)(pb + off + k);
        else return pk8(*(const float4*)(pf + off + k),
                        *(const float4*)(pf + off + k + 4));
    };

    uint4 xa0 = ldg(x, xbf, xo0, 0),  xa1 = ldg(x, xbf, xo1, 0);
    uint4 ka0 = ldg(Wk, wkbf, wo0, 0), ka1 = ldg(Wk, wkbf, wo1, 0);
    uint4 va0 = ldg(Wv, wvbf, wo0, 0), va1 = ldg(Wv, wvbf, wo1, 0);

    f32x4 kacc[2][2] = {};
    f32x4 vacc[2][2] = {};

    for (int k0 = 0; k0 < 512; k0 += 64) {
        __syncthreads();
        *(uint4*)(&As [r0     ][scol]) = xa0;
        *(uint4*)(&As [r0 + 32][scol]) = xa1;
        *(uint4*)(&Bks[r0     ][scol]) = ka0;
        *(uint4*)(&Bks[r0 + 32][scol]) = ka1;
        *(uint4*)(&Bvs[r0     ][scol]) = va0;
        *(uint4*)(&Bvs[r0 + 32][scol]) = va1;
        __syncthreads();
        if (k0 + 64 < 512) {
            xa0 = ldg(x, xbf, xo0, k0 + 64);  xa1 = ldg(x, xbf, xo1, k0 + 64);
            ka0 = ldg(Wk, wkbf, wo0, k0 + 64); ka1 = ldg(Wk, wkbf, wo1, k0 + 64);
            va0 = ldg(Wv, wvbf, wo0, k0 + 64); va1 = ldg(Wv, wvbf, wo1, k0 + 64);
        }

#pragma unroll
        for (int ks = 0; ks < 2; ++ks) {
            short8 afr[2], bkf[2], bvf[2];
#pragma unroll
            for (int mi = 0; mi < 2; ++mi)
                afr[mi] = *(const short8*)(&As[wm * 32 + mi * 16 + m15][ks * 32 + quad * 8]);
#pragma unroll
            for (int ni = 0; ni < 2; ++ni) {
                bkf[ni] = *(const short8*)(&Bks[wn * 32 + ni * 16 + m15][ks * 32 + quad * 8]);
                bvf[ni] = *(const short8*)(&Bvs[wn * 32 + ni * 16 + m15][ks * 32 + quad * 8]);
            }
#pragma unroll
            for (int mi = 0; mi < 2; ++mi)
#pragma unroll
                for (int ni = 0; ni < 2; ++ni) {
                    kacc[mi][ni] = __builtin_amdgcn_mfma_f32_16x16x32_bf16(
                        afr[mi], bkf[ni], kacc[mi][ni], 0, 0, 0);
                    vacc[mi][ni] = __builtin_amdgcn_mfma_f32_16x16x32_bf16(
                        afr[mi], bvf[ni], vacc[mi][ni], 0, 0, 0);
                }
        }
    }

    {
        u16* out = Kws + (size_t)blockIdx.x * (L_ * 64);
#pragma unroll
        for (int mi = 0; mi < 2; ++mi)
#pragma unroll
            for (int ni = 0; ni < 2; ++ni) {
                const int d  = wn * 32 + ni * 16 + m15;
                const float bv_ = bk[h * 64 + d];
#pragma unroll
                for (int r = 0; r < 4; ++r) {
                    const int l = l0 + wm * 32 + mi * 16 + quad * 4 + r;
                    out[(size_t)l * 64 + d] = f2b(kacc[mi][ni][r] + bv_);
                }
            }
    }
    __syncthreads();
#pragma unroll
    for (int mi = 0; mi < 2; ++mi)
#pragma unroll
        for (int ni = 0; ni < 2; ++ni) {
            const int d  = wn * 32 + ni * 16 + m15;
            const float bv_ = bv[h * 64 + d];
#pragma unroll
            for (int r = 0; r < 4; ++r)
                Ts[wm * 32 + mi * 16 + quad * 4 + r][d] = f2b(vacc[mi][ni][r] + bv_);
        }
    __syncthreads();
    {
        u16* Vt = Vws + (size_t)blockIdx.x * ((size_t)64 * L_);
        const int d  = t >> 2;
        const int ls = (t & 3) * 16;
        u16 pk[16];
#pragma unroll
        for (int j = 0; j < 16; ++j) pk[j] = Ts[ls + j][d];
        u16* dst = Vt + (size_t)d * L_ + l0 + ls;
        *(uint4*)dst       = *(const uint4*)pk;
        *(uint4*)(dst + 8) = *(const uint4*)(pk + 8);
    }
}

// ---------------------------------------------------------------------------
// Fused Q-projection + flash attention (R14 + A/B intra-wave pipeline).
// ---------------------------------------------------------------------------
template<bool BF>
__global__ __launch_bounds__(512, 4) void attn_kernel(
    const float* __restrict__ x, const u16* __restrict__ xbf,
    const float* __restrict__ Wq, const float* __restrict__ bq,
    const u16* __restrict__ wbf,
    const u16* __restrict__ Kws, const u16* __restrict__ Vws,
    const int* __restrict__ mask,
    float* __restrict__ O, u16* __restrict__ Obf, int bh0)
{
    __shared__ __align__(16) unsigned char sm[34816];
    u16 (*xs)[40]  = (u16(*)[40])sm;
    u16 (*wqs)[40] = (u16(*)[40])(sm + 10240);
    u16 (*Qs)[72]  = (u16(*)[72])sm;

    const int t    = threadIdx.x;
    const int wid  = t >> 6, lane = t & 63;
    const int m15  = lane & 15, quad = lane >> 4;
    const int l5   = lane & 31, hi = lane >> 5;
    const int hi4  = hi * 4;
    const int x7   = l5 & 7;
    const int qg   = wid & 3;
    const int kb   = wid >> 2;
    u16*   KsA  = (u16*)sm;
    u16*   KsB  = (u16*)(sm + 8192);
    u16*   VtsA = (u16*)(sm + 16384);
    u16*   VtsB = (u16*)(sm + 24576);
    float* Msb  = (float*)(sm + 32768);              // [128]
    float* AlfR = (float*)(sm + 33280) + wid * 32;

    const int bh = bh0 + blockIdx.y;
    const int b  = bh >> 3, h = bh & 7;
    const int q0 = blockIdx.x * 128;
    const u16* Kc  = Kws + (size_t)blockIdx.y * (L_ * 64);
    const u16* Vtc = Vws + (size_t)blockIdx.y * ((size_t)64 * L_);

    const int srow  = t >> 3;
    const int scol8 = (t & 7);
    const int sslot = (scol8 ^ (srow & 7)) * 8;

    uint4 kregA = *(const uint4*)(Kc + (size_t)srow * 64 + scol8 * 8);
    uint4 vregA = *(const uint4*)(Vtc + (size_t)srow * L_ + scol8 * 8);
    uint4 kregB = *(const uint4*)(Kc + (size_t)(64 + srow) * 64 + scol8 * 8);
    uint4 vregB = *(const uint4*)(Vtc + (size_t)srow * L_ + 64 + scol8 * 8);
    int mregA = 0, mregB = 0;
    if (t < 64) {
        mregA = mask[b * L_ + t];
        mregB = mask[b * L_ + 64 + t];
    }

    // ---- phase 1: Q[128][64] = x @ Wq[h]^T ----
    f32x4 qacc[4] = {};
    {
        const int xr = t >> 2, xc = (t & 3) * 8;
        const size_t xoff = ((size_t)b * L_ + q0 + xr) * 512 + xc;
        const size_t woff = (size_t)(h * 64 + xr) * 512 + xc;   // valid t<256
        auto ldx = [&](int k) -> uint4 {
            if constexpr (BF) return *(const uint4*)(xbf + xoff + k);
            else return pk8(*(const float4*)(x + xoff + k),
                            *(const float4*)(x + xoff + k + 4));
        };
        auto ldw = [&](int k) -> uint4 {
            if constexpr (BF) return *(const uint4*)(wbf + woff + k);
            else return pk8(*(const float4*)(Wq + woff + k),
                            *(const float4*)(Wq + woff + k + 4));
        };
        uint4 xaR = ldx(0);
        uint4 waR = {};
        if (t < 256) waR = ldw(0);
        for (int k0 = 0; k0 < 512; k0 += 32) {
            __syncthreads();
            *(uint4*)(&xs[xr][xc]) = xaR;
            if (t < 256) *(uint4*)(&wqs[xr][xc]) = waR;
            __syncthreads();
            if (k0 + 32 < 512) {
                xaR = ldx(k0 + 32);
                if (t < 256) waR = ldw(k0 + 32);
            }
            const short8 afr = *(const short8*)(&xs[wid * 16 + m15][quad * 8]);
#pragma unroll
            for (int ni = 0; ni < 4; ++ni) {
                const short8 bfr = *(const short8*)(&wqs[ni * 16 + m15][quad * 8]);
                qacc[ni] = __builtin_amdgcn_mfma_f32_16x16x32_bf16(afr, bfr, qacc[ni], 0, 0, 0);
            }
        }
    }

    // ---- phase 1b: bounce Q through LDS into 32x32 B-frags ----
    const float QSCALE = 0.125f * 1.44269504089f;    // /sqrt(dk) * log2(e)
    __syncthreads();
#pragma unroll
    for (int ni = 0; ni < 4; ++ni) {
        const float bv_ = bq[h * 64 + ni * 16 + m15];
#pragma unroll
        for (int r = 0; r < 4; ++r)
            Qs[wid * 16 + quad * 4 + r][ni * 16 + m15] =
                f2b((qacc[ni][r] + bv_) * QSCALE);
    }
    __syncthreads();
    short8 qfr[4];
#pragma unroll
    for (int kd = 0; kd < 4; ++kd)
        qfr[kd] = *(const short8*)(&Qs[32 * qg + l5][16 * kd + 8 * hi]);

    // ---- flash state ----
    float m_i = -1e30f, l_i = 0.0f;
    f32x16 oacc[2];
#pragma unroll
    for (int db = 0; db < 2; ++db)
#pragma unroll
        for (int e = 0; e < 16; ++e) oacc[db][e] = 0.0f;

    // QK^T for one 64-key tile (C-init with mask bias) -> S^T fragment.
    auto qk_tile = [&](const u16* KsC, const float* MsbC) -> f32x16 {
        f32x16 sa;
#pragma unroll
        for (int p = 0; p < 4; ++p) {
            const f32x4 bb = *(const f32x4*)(MsbC + 32 * kb + 8 * p + hi4);
            sa[4*p+0] = bb[0]; sa[4*p+1] = bb[1]; sa[4*p+2] = bb[2]; sa[4*p+3] = bb[3];
        }
        __builtin_amdgcn_s_setprio(1);
#pragma unroll
        for (int kd = 0; kd < 4; ++kd) {
            const short8 kf = *(const short8*)(
                KsC + (size_t)(32 * kb + l5) * 64 + (((2 * kd + hi) ^ x7)) * 8);
            sa = __builtin_amdgcn_mfma_f32_32x32x16_bf16(kf, qfr[kd], sa, 0, 0, 0);
        }
        __builtin_amdgcn_s_setprio(0);
        return sa;
    };

    // softmax + PV for one tile (updates m_i, l_i, oacc).
    auto sm_pv = [&](const f32x16& sa, const u16* VtsC) {
        float mx = fmaxf(
            fmaxf(fmaxf(fmaxf(sa[0], sa[1]),  fmaxf(sa[2], sa[3])),
                  fmaxf(fmaxf(sa[4], sa[5]),  fmaxf(sa[6], sa[7]))),
            fmaxf(fmaxf(fmaxf(sa[8], sa[9]),  fmaxf(sa[10], sa[11])),
                  fmaxf(fmaxf(sa[12], sa[13]), fmaxf(sa[14], sa[15]))));
        mx = fmaxf(mx, __shfl_xor(mx, 32));

        if (__any(mx > m_i + 8.0f)) {      // T13 threshold defer-rescale
            const float mnew = fmaxf(m_i, mx);
            const float a = EX2(m_i - mnew);
            m_i = mnew;
            l_i *= a;
            if (hi == 0) AlfR[l5] = a;
#pragma unroll
            for (int p = 0; p < 4; ++p) {
                const f32x4 a4 = *(const f32x4*)(&AlfR[8 * p + hi4]);
#pragma unroll
                for (int i = 0; i < 4; ++i) {
                    oacc[0][4*p+i] *= a4[i];
                    oacc[1][4*p+i] *= a4[i];
                }
            }
        }

        float pv[16];
#pragma unroll
        for (int r = 0; r < 16; ++r) pv[r] = EX2(sa[r] - m_i);
        float ss = ((pv[0]+pv[1]) + (pv[2]+pv[3])) + ((pv[4]+pv[5]) + (pv[6]+pv[7]))
                 + ((pv[8]+pv[9]) + (pv[10]+pv[11])) + ((pv[12]+pv[13]) + (pv[14]+pv[15]));
        ss += __shfl_xor(ss, 32);
        l_i += ss;

        unsigned W[8];
#pragma unroll
        for (int m = 0; m < 8; ++m) W[m] = cvt_pk_bf16(pv[2*m], pv[2*m+1]);

#pragma unroll
        for (int c1 = 0; c1 < 2; ++c1) {
            const unsigned X  = hi ? W[4*c1+0] : W[4*c1+2];
            const unsigned Y  = hi ? W[4*c1+1] : W[4*c1+3];
            const unsigned Xp = __shfl_xor((int)X, 32);
            const unsigned Yp = __shfl_xor((int)Y, 32);
            const unsigned w0 = hi ? Xp : W[4*c1+0];
            const unsigned w1 = hi ? Yp : W[4*c1+1];
            const unsigned w2 = hi ? W[4*c1+2] : Xp;
            const unsigned w3 = hi ? W[4*c1+3] : Yp;
            const short8 af = mk8(w0, w1, w2, w3);
            const int kcg = 2 * kb + c1;
            __builtin_amdgcn_s_setprio(1);
#pragma unroll
            for (int db = 0; db < 2; ++db) {
                const short8 vf = *(const short8*)(
                    VtsC + (size_t)(32 * db + l5) * 64 + (((2 * kcg + hi) ^ x7)) * 8);
                oacc[db] = __builtin_amdgcn_mfma_f32_32x32x16_bf16(af, vf, oacc[db], 0, 0, 0);
            }
            __builtin_amdgcn_s_setprio(0);
        }
    };

    // ---- flash loop: 32 super-tiles of 128 keys; 2 barriers each.
    //      A/B pipeline: QK_A, QK_B issue together; SM/PV in order. ----
    for (int it = 0; it < 32; ++it) {
        __syncthreads();
        *(uint4*)(KsA  + srow * 64 + sslot) = kregA;
        *(uint4*)(VtsA + srow * 64 + sslot) = vregA;
        *(uint4*)(KsB  + srow * 64 + sslot) = kregB;
        *(uint4*)(VtsB + srow * 64 + sslot) = vregB;
        if (t < 64) {
            Msb[t]      = (mregA == 0) ? -14427.0f : 0.0f;
            Msb[64 + t] = (mregB == 0) ? -14427.0f : 0.0f;
        }
        __syncthreads();
        if (it + 1 < 32) {
            const int kA = (it + 1) * 128, kB = kA + 64;
            kregA = *(const uint4*)(Kc + (size_t)(kA + srow) * 64 + scol8 * 8);
            vregA = *(const uint4*)(Vtc + (size_t)srow * L_ + kA + scol8 * 8);
            kregB = *(const uint4*)(Kc + (size_t)(kB + srow) * 64 + scol8 * 8);
            vregB = *(const uint4*)(Vtc + (size_t)srow * L_ + kB + scol8 * 8);
            if (t < 64) {
                mregA = mask[b * L_ + kA + t];
                mregB = mask[b * L_ + kB + t];
            }
        }
        const f32x16 saA = qk_tile(KsA, Msb);
        const f32x16 saB = qk_tile(KsB, Msb + 64);   // hides under SM_A
        sm_pv(saA, VtsA);
        sm_pv(saB, VtsB);
    }

    // ---- merge the two key-streams (exact flash-combine), write output ----
    float* Op  = (float*)sm;
    float* Mp0 = (float*)(sm + 32768);
    float* Mp1 = Mp0 + 128;
    float* FA  = (float*)(sm + 33792);
    float* FB  = FA + 128;

    __syncthreads();
    if (wid >= 4) {
#pragma unroll
        for (int db = 0; db < 2; ++db) {
            const int d = 32 * db + l5;
#pragma unroll
            for (int p = 0; p < 4; ++p) {
                const int qb   = 32 * qg + 8 * p + hi4;
                const int slot = (qb >> 2) ^ l5;
                f32x4 v;
#pragma unroll
                for (int i = 0; i < 4; ++i) v[i] = oacc[db][4*p+i];
                *(f32x4*)(&Op[d * 128 + slot * 4]) = v;
            }
        }
        if (hi == 0) { Mp0[32 * qg + l5] = m_i; Mp1[32 * qg + l5] = l_i; }
    }
    __syncthreads();
    if (wid < 4) {
        const int q5 = 32 * qg + l5;
        const float mB = Mp0[q5], lB = Mp1[q5];
        const float mS = fmaxf(m_i, mB);
        const float aA = EX2(m_i - mS), aB = EX2(mB - mS);
        const float linv = 1.0f / (l_i * aA + lB * aB);
        if (hi == 0) { FA[q5] = aA * linv; FB[q5] = aB * linv; }
#pragma unroll
        for (int db = 0; db < 2; ++db) {
            const int d = 32 * db + l5;
            const int col = h * 64 + d;
#pragma unroll
            for (int p = 0; p < 4; ++p) {
                const int qb   = 32 * qg + 8 * p + hi4;
                const f32x4 fa = *(const f32x4*)(&FA[qb]);
                const f32x4 fb = *(const f32x4*)(&FB[qb]);
                const int slot = (qb >> 2) ^ l5;
                const f32x4 ob = *(const f32x4*)(&Op[d * 128 + slot * 4]);
#pragma unroll
                for (int i = 0; i < 4; ++i) {
                    const float val = oacc[db][4*p+i] * fa[i] + ob[i] * fb[i];
                    const size_t row = (size_t)b * L_ + q0 + qb + i;
                    if (Obf) Obf[row * 512 + col] = f2b(val);
                    else     O  [row * 512 + col] = val;
                }
            }
        }
    }
}

// ---------------------------------------------------------------------------
// Output projection v2, K-chunk 64 (verbatim R14).
// ---------------------------------------------------------------------------
template<bool BF>
__global__ __launch_bounds__(256) void outproj_v2_kernel(
    const u16* __restrict__ AO,
    const float* __restrict__ Wo, const u16* __restrict__ wobf,
    const float* __restrict__ bo,
    float* __restrict__ out)
{
    __shared__ __align__(16) unsigned char sm[18432];
    u16 (*As)[72] = (u16(*)[72])sm;
    u16 (*Bs)[72] = (u16(*)[72])(sm + 9216);

    const int t    = threadIdx.x;
    const int wid  = t >> 6, lane = t & 63;
    const int m15  = lane & 15, quad = lane >> 4;
    const int wm   = wid >> 1, wn = wid & 1;
    const int bm   = blockIdx.x * 64;
    const int n0   = blockIdx.y * 64;

    const int r0   = t >> 3;
    const int scol = (t & 7) * 8;

    const size_t ao0 = (size_t)(bm + r0) * 512 + scol;
    const size_t ao1 = ao0 + (size_t)32 * 512;
    const size_t bo0 = (size_t)(n0 + r0) * 512 + scol;
    const size_t bo1 = bo0 + (size_t)32 * 512;

    auto ldb = [&](size_t off, int k) -> uint4 {
        if constexpr (BF) return *(const uint4*)(wobf + off + k);
        else return pk8(*(const float4*)(Wo + off + k),
                        *(const float4*)(Wo + off + k + 4));
    };

    uint4 a0 = *(const uint4*)(AO + ao0), a1 = *(const uint4*)(AO + ao1);
    uint4 b0 = ldb(bo0, 0), b1 = ldb(bo1, 0);

    f32x4 acc[2][2] = {};

    for (int k0 = 0; k0 < 512; k0 += 64) {
        __syncthreads();
        *(uint4*)(&As[r0     ][scol]) = a0;
        *(uint4*)(&As[r0 + 32][scol]) = a1;
        *(uint4*)(&Bs[r0     ][scol]) = b0;
        *(uint4*)(&Bs[r0 + 32][scol]) = b1;
        __syncthreads();
        if (k0 + 64 < 512) {
            a0 = *(const uint4*)(AO + ao0 + k0 + 64);
            a1 = *(const uint4*)(AO + ao1 + k0 + 64);
            b0 = ldb(bo0, k0 + 64);
            b1 = ldb(bo1, k0 + 64);
        }

#pragma unroll
        for (int ks = 0; ks < 2; ++ks) {
            short8 afr[2], bfr[2];
#pragma unroll
            for (int mi = 0; mi < 2; ++mi)
                afr[mi] = *(const short8*)(&As[wm * 32 + mi * 16 + m15][ks * 32 + quad * 8]);
#pragma unroll
            for (int ni = 0; ni < 2; ++ni)
                bfr[ni] = *(const short8*)(&Bs[wn * 32 + ni * 16 + m15][ks * 32 + quad * 8]);
#pragma unroll
            for (int mi = 0; mi < 2; ++mi)
#pragma unroll
                for (int ni = 0; ni < 2; ++ni)
                    acc[mi][ni] = __builtin_amdgcn_mfma_f32_16x16x32_bf16(
                        afr[mi], bfr[ni], acc[mi][ni], 0, 0, 0);
        }
    }

#pragma unroll
    for (int mi = 0; mi < 2; ++mi)
#pragma unroll
        for (int ni = 0; ni < 2; ++ni) {
            const int col = n0 + wn * 32 + ni * 16 + m15;
            const float bv_ = bo[col];
#pragma unroll
            for (int r = 0; r < 4; ++r) {
                const int row = bm + wm * 32 + mi * 16 + quad * 4 + r;
                out[(size_t)row * 512 + col] = acc[mi][ni][r] + bv_;
            }
        }
}

// ---------------------------------------------------------------------------
// Fallback in-place fp32 output projection (unchanged).
// ---------------------------------------------------------------------------
__global__ __launch_bounds__(256) void outproj_inplace_kernel(
    float* __restrict__ AO,
    const float* __restrict__ Wo, const float* __restrict__ bo)
{
    __shared__ __align__(16) u16 As[32][520];
    __shared__ __align__(16) u16 Ws_[64][40];

    const int t    = threadIdx.x;
    const int wid  = t >> 6, lane = t & 63;
    const int m15  = lane & 15, quad = lane >> 4;
    const int wm   = wid >> 1, wn = wid & 1;
    const int bm   = blockIdx.x * 32;

#pragma unroll
    for (int it = 0; it < 8; ++it) {
        const int idx = t + it * 256;
        const int row = idx >> 6, c8 = (idx & 63) * 8;
        stage8f(&As[row][c8], AO + (size_t)(bm + row) * 512 + c8);
    }
    const int lrow = t >> 2;
    const int lcol = (t & 3) * 8;
    __syncthreads();

    for (int n0 = 0; n0 < 512; n0 += 64) {
        f32x4 acc[2] = {};
        for (int k0 = 0; k0 < 512; k0 += 32) {
            __syncthreads();
            stage8f(&Ws_[lrow][lcol], Wo + (size_t)(n0 + lrow) * 512 + k0 + lcol);
            __syncthreads();
            const short8 afr = *(const short8*)(&As[wm * 16 + m15][k0 + quad * 8]);
#pragma unroll
            for (int ni = 0; ni < 2; ++ni) {
                const short8 bfr = *(const short8*)(&Ws_[wn * 32 + ni * 16 + m15][quad * 8]);
                acc[ni] = __builtin_amdgcn_mfma_f32_16x16x32_bf16(afr, bfr, acc[ni], 0, 0, 0);
            }
        }
#pragma unroll
        for (int ni = 0; ni < 2; ++ni) {
            const int col = n0 + wn * 32 + ni * 16 + m15;
            const float bv_ = bo[col];
#pragma unroll
            for (int r = 0; r < 4; ++r) {
                const int row = bm + wm * 16 + quad * 4 + r;
                AO[(size_t)row * 512 + col] = acc[ni][r] + bv_;
            }
        }
    }
}

extern "C" void kernel_launch(void* const* d_in, const int* in_sizes, int n_in,
                              void* d_out, int out_size, void* d_ws, size_t ws_size,
                              hipStream_t stream) {
    const float* x    = (const float*)d_in[0];
    const int*   mask = (const int*)d_in[1];
    const float* Wq = (const float*)d_in[2]; const float* bq = (const float*)d_in[3];
    const float* Wk = (const float*)d_in[4]; const float* bk = (const float*)d_in[5];
    const float* Wv = (const float*)d_in[6]; const float* bv = (const float*)d_in[7];
    const float* Wo = (const float*)d_in[8]; const float* bo = (const float*)d_in[9];

    float* out = (float*)d_out;
    u16*   ws  = (u16*)d_ws;

    const size_t per_bh   = (size_t)2 * L_ * 64 * 2;
    const size_t kv_bytes = (size_t)BH_ * per_bh;           // 16 MiB
    const size_t ao_bytes = (size_t)M_ * 512 * 2;           // 8 MiB
    const size_t NX = (size_t)B_ * L_ * D_;
    const size_t NW = (size_t)D_ * D_;

    if (ws_size >= kv_bytes + ao_bytes) {
        u16* Kws  = ws;
        u16* Vws  = Kws + (size_t)BH_ * (L_ * 64);
        u16* AOws = ws + kv_bytes / 2;
        const bool can_prep = (size_t)out_size >= (NX + 3 * NW) * 2;
        u16* wobf = (ws_size >= kv_bytes + ao_bytes + NW * 2)
                        ? ws + (kv_bytes + ao_bytes) / 2 : nullptr;

        if (can_prep) {
            u16* xbf = (u16*)d_out;
            u16* wbf = xbf + NX;
            const int pgrid = (int)((NX + 4 * NW) / 2048);
            prep_kernel<<<pgrid, 256, 0, stream>>>(x, Wq, Wk, Wv, Wo,
                                                   xbf, wbf, wobf);
            kvproj_kernel<true><<<dim3(BH_, L_ / 64), 256, 0, stream>>>(
                x, xbf, Wk, bk, Wv, bv, wbf, Kws, Vws, 0);
            attn_kernel<true><<<dim3(L_ / 128, BH_), 512, 0, stream>>>(
                x, xbf, Wq, bq, wbf, Kws, Vws, mask, out, AOws, 0);
        } else {
            kvproj_kernel<false><<<dim3(BH_, L_ / 64), 256, 0, stream>>>(
                x, nullptr, Wk, bk, Wv, bv, nullptr, Kws, Vws, 0);
            attn_kernel<false><<<dim3(L_ / 128, BH_), 512, 0, stream>>>(
                x, nullptr, Wq, bq, nullptr, Kws, Vws, mask, out, AOws, 0);
        }
        if (wobf && can_prep)
            outproj_v2_kernel<true><<<dim3(M_ / 64, 8), 256, 0, stream>>>(
                AOws, Wo, wobf, bo, out);
        else
            outproj_v2_kernel<false><<<dim3(M_ / 64, 8), 256, 0, stream>>>(
                AOws, Wo, nullptr, bo, out);
    } else {
        int chunk = 16;
        while (chunk > 1 && (size_t)chunk * per_bh > ws_size) chunk >>= 1;
        u16* Kws = ws;
        u16* Vws = Kws + (size_t)chunk * (L_ * 64);
        for (int bh0 = 0; bh0 < BH_; bh0 += chunk) {
            kvproj_kernel<false><<<dim3(chunk, L_ / 64), 256, 0, stream>>>(
                x, nullptr, Wk, bk, Wv, bv, nullptr, Kws, Vws, bh0);
            attn_kernel<false><<<dim3(L_ / 128, chunk), 512, 0, stream>>>(
                x, nullptr, Wq, bq, nullptr, Kws, Vws, mask, out, nullptr, bh0);
        }
        outproj_inplace_kernel<<<dim3(M_ / 32), 256, 0, stream>>>(out, Wo, bo);
    }
}

// Round 16
// 224.789 us; speedup vs baseline: 1.2181x; 1.2181x over previous
//
#include <hip/hip_runtime.h>

// Round 31: revert R15's A/B pipeline (VGPR spill: WRITE_SIZE 8MB->196MB,
// attn 131->179us). Base = R14 verbatim (verified 232.6us best).
// One low-risk addition: attn phase-1 K-chunk 32->64 (16 barriers, was 32;
// same pattern as the R13 kvproj win). Bit-identical K-order accumulation;
// LDS ph1 = xs[128][72] (18432) + wqs[64][72] (9216) = 27648 < 34816.

#define B_  2
#define L_  4096
#define D_  512
#define H_  8
#define BH_ 16
#define M_  8192

typedef __attribute__((ext_vector_type(8)))  short short8;   // 8 bf16
typedef __attribute__((ext_vector_type(4)))  float f32x4;
typedef __attribute__((ext_vector_type(16))) float f32x16;
typedef unsigned short u16;

#if __has_builtin(__builtin_amdgcn_exp2f)
#define EX2(x) __builtin_amdgcn_exp2f(x)
#else
#define EX2(x) exp2f(x)
#endif

static __device__ __forceinline__ u16 f2b(float f) {
    union { float f; unsigned i; } x; x.f = f;
    unsigned r = x.i + 0x7fff + ((x.i >> 16) & 1);   // RNE
    return (u16)(r >> 16);
}

static __device__ __forceinline__ unsigned cvt_pk_bf16(float lo, float hi) {
    unsigned r;
    asm("v_cvt_pk_bf16_f32 %0, %1, %2" : "=v"(r) : "v"(lo), "v"(hi));
    return r;
}

static __device__ __forceinline__ uint4 pk8(const float4& a, const float4& b) {
    uint4 o;
    o.x = cvt_pk_bf16(a.x, a.y);
    o.y = cvt_pk_bf16(a.z, a.w);
    o.z = cvt_pk_bf16(b.x, b.y);
    o.w = cvt_pk_bf16(b.z, b.w);
    return o;
}

static __device__ __forceinline__ void stage8f(u16* dst, const float* s) {
    const float4 a = *(const float4*)s;
    const float4 b = *(const float4*)(s + 4);
    *(uint4*)dst = pk8(a, b);
}

static __device__ __forceinline__ short8 mk8(unsigned a, unsigned b,
                                             unsigned c, unsigned d) {
    union { unsigned u[4]; short8 s; } x;
    x.u[0] = a; x.u[1] = b; x.u[2] = c; x.u[3] = d;
    return x.s;
}

// ---------------------------------------------------------------------------
// Prep: fp32 -> bf16 one-shot conversion (verbatim R14).
// ---------------------------------------------------------------------------
__global__ __launch_bounds__(256) void prep_kernel(
    const float* __restrict__ x,
    const float* __restrict__ Wq, const float* __restrict__ Wk,
    const float* __restrict__ Wv, const float* __restrict__ Wo,
    u16* __restrict__ xbf, u16* __restrict__ wbf, u16* __restrict__ wobf)
{
    const size_t NX = (size_t)B_ * L_ * D_;
    const size_t NW = (size_t)D_ * D_;
    const size_t i8 = ((size_t)blockIdx.x * 256 + threadIdx.x) * 8;
    const float* s; u16* d;
    if (i8 < NX) { s = x + i8; d = xbf + i8; }
    else {
        const size_t j = i8 - NX;
        if      (j <     NW) { s = Wq + j;          d = wbf + j; }
        else if (j < 2 * NW) { s = Wk + (j - NW);   d = wbf + j; }
        else if (j < 3 * NW) { s = Wv + (j - 2*NW); d = wbf + j; }
        else if (j < 4 * NW) {
            if (!wobf) return;
            s = Wo + (j - 3*NW); d = wobf + (j - 3*NW);
        } else return;
    }
    *(uint4*)d = pk8(*(const float4*)s, *(const float4*)(s + 4));
}

// ---------------------------------------------------------------------------
// Fused K+V projection, K-chunk 64 (verbatim R14).
// ---------------------------------------------------------------------------
template<bool BF>
__global__ __launch_bounds__(256) void kvproj_kernel(
    const float* __restrict__ x, const u16* __restrict__ xbf,
    const float* __restrict__ Wk, const float* __restrict__ bk,
    const float* __restrict__ Wv, const float* __restrict__ bv,
    const u16* __restrict__ wbf,
    u16* __restrict__ Kws, u16* __restrict__ Vws, int bh0)
{
    __shared__ __align__(16) unsigned char sm[27648];
    u16 (*As)[72]  = (u16(*)[72])sm;
    u16 (*Bks)[72] = (u16(*)[72])(sm + 9216);
    u16 (*Bvs)[72] = (u16(*)[72])(sm + 18432);
    u16 (*Ts)[73]  = (u16(*)[73])sm;

    const int t    = threadIdx.x;
    const int wid  = t >> 6, lane = t & 63;
    const int m15  = lane & 15, quad = lane >> 4;
    const int wm   = wid >> 1, wn = wid & 1;

    const int bh = bh0 + blockIdx.x;
    const int b  = bh >> 3, h = bh & 7;
    const int l0 = blockIdx.y * 64;

    const int r0   = t >> 3;
    const int scol = (t & 7) * 8;

    const size_t xo0 = ((size_t)b * L_ + l0 + r0) * 512 + scol;
    const size_t xo1 = xo0 + (size_t)32 * 512;
    const size_t wo0 = (size_t)(h * 64 + r0) * 512 + scol;
    const size_t wo1 = wo0 + (size_t)32 * 512;
    const u16* wkbf = wbf + 262144;
    const u16* wvbf = wbf + 2 * 262144;

    auto ldg = [&](const float* pf, const u16* pb, size_t off, int k) -> uint4 {
        if constexpr (BF) return *(const uint4*)(pb + off + k);
        else return pk8(*(const float4*)(pf + off + k),
                        *(const float4*)(pf + off + k + 4));
    };

    uint4 xa0 = ldg(x, xbf, xo0, 0),  xa1 = ldg(x, xbf, xo1, 0);
    uint4 ka0 = ldg(Wk, wkbf, wo0, 0), ka1 = ldg(Wk, wkbf, wo1, 0);
    uint4 va0 = ldg(Wv, wvbf, wo0, 0), va1 = ldg(Wv, wvbf, wo1, 0);

    f32x4 kacc[2][2] = {};
    f32x4 vacc[2][2] = {};

    for (int k0 = 0; k0 < 512; k0 += 64) {
        __syncthreads();
        *(uint4*)(&As [r0     ][scol]) = xa0;
        *(uint4*)(&As [r0 + 32][scol]) = xa1;
        *(uint4*)(&Bks[r0     ][scol]) = ka0;
        *(uint4*)(&Bks[r0 + 32][scol]) = ka1;
        *(uint4*)(&Bvs[r0     ][scol]) = va0;
        *(uint4*)(&Bvs[r0 + 32][scol]) = va1;
        __syncthreads();
        if (k0 + 64 < 512) {
            xa0 = ldg(x, xbf, xo0, k0 + 64);  xa1 = ldg(x, xbf, xo1, k0 + 64);
            ka0 = ldg(Wk, wkbf, wo0, k0 + 64); ka1 = ldg(Wk, wkbf, wo1, k0 + 64);
            va0 = ldg(Wv, wvbf, wo0, k0 + 64); va1 = ldg(Wv, wvbf, wo1, k0 + 64);
        }

#pragma unroll
        for (int ks = 0; ks < 2; ++ks) {
            short8 afr[2], bkf[2], bvf[2];
#pragma unroll
            for (int mi = 0; mi < 2; ++mi)
                afr[mi] = *(const short8*)(&As[wm * 32 + mi * 16 + m15][ks * 32 + quad * 8]);
#pragma unroll
            for (int ni = 0; ni < 2; ++ni) {
                bkf[ni] = *(const short8*)(&Bks[wn * 32 + ni * 16 + m15][ks * 32 + quad * 8]);
                bvf[ni] = *(const short8*)(&Bvs[wn * 32 + ni * 16 + m15][ks * 32 + quad * 8]);
            }
#pragma unroll
            for (int mi = 0; mi < 2; ++mi)
#pragma unroll
                for (int ni = 0; ni < 2; ++ni) {
                    kacc[mi][ni] = __builtin_amdgcn_mfma_f32_16x16x32_bf16(
                        afr[mi], bkf[ni], kacc[mi][ni], 0, 0, 0);
                    vacc[mi][ni] = __builtin_amdgcn_mfma_f32_16x16x32_bf16(
                        afr[mi], bvf[ni], vacc[mi][ni], 0, 0, 0);
                }
        }
    }

    {
        u16* out = Kws + (size_t)blockIdx.x * (L_ * 64);
#pragma unroll
        for (int mi = 0; mi < 2; ++mi)
#pragma unroll
            for (int ni = 0; ni < 2; ++ni) {
                const int d  = wn * 32 + ni * 16 + m15;
                const float bv_ = bk[h * 64 + d];
#pragma unroll
                for (int r = 0; r < 4; ++r) {
                    const int l = l0 + wm * 32 + mi * 16 + quad * 4 + r;
                    out[(size_t)l * 64 + d] = f2b(kacc[mi][ni][r] + bv_);
                }
            }
    }
    __syncthreads();
#pragma unroll
    for (int mi = 0; mi < 2; ++mi)
#pragma unroll
        for (int ni = 0; ni < 2; ++ni) {
            const int d  = wn * 32 + ni * 16 + m15;
            const float bv_ = bv[h * 64 + d];
#pragma unroll
            for (int r = 0; r < 4; ++r)
                Ts[wm * 32 + mi * 16 + quad * 4 + r][d] = f2b(vacc[mi][ni][r] + bv_);
        }
    __syncthreads();
    {
        u16* Vt = Vws + (size_t)blockIdx.x * ((size_t)64 * L_);
        const int d  = t >> 2;
        const int ls = (t & 3) * 16;
        u16 pk[16];
#pragma unroll
        for (int j = 0; j < 16; ++j) pk[j] = Ts[ls + j][d];
        u16* dst = Vt + (size_t)d * L_ + l0 + ls;
        *(uint4*)dst       = *(const uint4*)pk;
        *(uint4*)(dst + 8) = *(const uint4*)(pk + 8);
    }
}

// ---------------------------------------------------------------------------
// Fused Q-projection + flash attention (R14 + phase-1 K-chunk 64).
// ---------------------------------------------------------------------------
template<bool BF>
__global__ __launch_bounds__(512, 4) void attn_kernel(
    const float* __restrict__ x, const u16* __restrict__ xbf,
    const float* __restrict__ Wq, const float* __restrict__ bq,
    const u16* __restrict__ wbf,
    const u16* __restrict__ Kws, const u16* __restrict__ Vws,
    const int* __restrict__ mask,
    float* __restrict__ O, u16* __restrict__ Obf, int bh0)
{
    __shared__ __align__(16) unsigned char sm[34816];
    u16 (*xs)[72]  = (u16(*)[72])sm;                 // ph1, 18432 B
    u16 (*wqs)[72] = (u16(*)[72])(sm + 18432);       // ph1, 9216 B
    u16 (*Qs)[72]  = (u16(*)[72])sm;                 // ph1b (overlays xs)

    const int t    = threadIdx.x;
    const int wid  = t >> 6, lane = t & 63;
    const int m15  = lane & 15, quad = lane >> 4;
    const int l5   = lane & 31, hi = lane >> 5;
    const int hi4  = hi * 4;
    const int x7   = l5 & 7;
    const int qg   = wid & 3;
    const int kb   = wid >> 2;
    u16*   KsA  = (u16*)sm;
    u16*   KsB  = (u16*)(sm + 8192);
    u16*   VtsA = (u16*)(sm + 16384);
    u16*   VtsB = (u16*)(sm + 24576);
    float* Msb  = (float*)(sm + 32768);              // [128]
    float* AlfR = (float*)(sm + 33280) + wid * 32;

    const int bh = bh0 + blockIdx.y;
    const int b  = bh >> 3, h = bh & 7;
    const int q0 = blockIdx.x * 128;
    const u16* Kc  = Kws + (size_t)blockIdx.y * (L_ * 64);
    const u16* Vtc = Vws + (size_t)blockIdx.y * ((size_t)64 * L_);

    const int srow  = t >> 3;
    const int scol8 = (t & 7);
    const int sslot = (scol8 ^ (srow & 7)) * 8;

    uint4 kregA = *(const uint4*)(Kc + (size_t)srow * 64 + scol8 * 8);
    uint4 vregA = *(const uint4*)(Vtc + (size_t)srow * L_ + scol8 * 8);
    uint4 kregB = *(const uint4*)(Kc + (size_t)(64 + srow) * 64 + scol8 * 8);
    uint4 vregB = *(const uint4*)(Vtc + (size_t)srow * L_ + 64 + scol8 * 8);
    int mregA = 0, mregB = 0;
    if (t < 64) {
        mregA = mask[b * L_ + t];
        mregB = mask[b * L_ + 64 + t];
    }

    // ---- phase 1: Q[128][64] = x @ Wq[h]^T, K-chunk 64 (16 barriers) ----
    f32x4 qacc[4] = {};
    {
        const int xr = t >> 2, xc = (t & 3) * 8;     // cols xc and xc+32
        const size_t xoff = ((size_t)b * L_ + q0 + xr) * 512 + xc;
        const size_t woff = (size_t)(h * 64 + xr) * 512 + xc;   // valid t<256
        auto ldx = [&](int k) -> uint4 {
            if constexpr (BF) return *(const uint4*)(xbf + xoff + k);
            else return pk8(*(const float4*)(x + xoff + k),
                            *(const float4*)(x + xoff + k + 4));
        };
        auto ldw = [&](int k) -> uint4 {
            if constexpr (BF) return *(const uint4*)(wbf + woff + k);
            else return pk8(*(const float4*)(Wq + woff + k),
                            *(const float4*)(Wq + woff + k + 4));
        };
        uint4 xa0 = ldx(0), xa1 = ldx(32);
        uint4 wa0 = {}, wa1 = {};
        if (t < 256) { wa0 = ldw(0); wa1 = ldw(32); }
        for (int k0 = 0; k0 < 512; k0 += 64) {
            __syncthreads();
            *(uint4*)(&xs[xr][xc])      = xa0;
            *(uint4*)(&xs[xr][xc + 32]) = xa1;
            if (t < 256) {
                *(uint4*)(&wqs[xr][xc])      = wa0;
                *(uint4*)(&wqs[xr][xc + 32]) = wa1;
            }
            __syncthreads();
            if (k0 + 64 < 512) {
                xa0 = ldx(k0 + 64); xa1 = ldx(k0 + 96);
                if (t < 256) { wa0 = ldw(k0 + 64); wa1 = ldw(k0 + 96); }
            }
#pragma unroll
            for (int ks = 0; ks < 2; ++ks) {
                const short8 afr = *(const short8*)(&xs[wid * 16 + m15][ks * 32 + quad * 8]);
#pragma unroll
                for (int ni = 0; ni < 4; ++ni) {
                    const short8 bfr = *(const short8*)(&wqs[ni * 16 + m15][ks * 32 + quad * 8]);
                    qacc[ni] = __builtin_amdgcn_mfma_f32_16x16x32_bf16(afr, bfr, qacc[ni], 0, 0, 0);
                }
            }
        }
    }

    // ---- phase 1b: bounce Q through LDS into 32x32 B-frags ----
    const float QSCALE = 0.125f * 1.44269504089f;    // /sqrt(dk) * log2(e)
    __syncthreads();
#pragma unroll
    for (int ni = 0; ni < 4; ++ni) {
        const float bv_ = bq[h * 64 + ni * 16 + m15];
#pragma unroll
        for (int r = 0; r < 4; ++r)
            Qs[wid * 16 + quad * 4 + r][ni * 16 + m15] =
                f2b((qacc[ni][r] + bv_) * QSCALE);
    }
    __syncthreads();
    short8 qfr[4];
#pragma unroll
    for (int kd = 0; kd < 4; ++kd)
        qfr[kd] = *(const short8*)(&Qs[32 * qg + l5][16 * kd + 8 * hi]);

    // ---- flash state ----
    float m_i = -1e30f, l_i = 0.0f;
    f32x16 oacc[2];
#pragma unroll
    for (int db = 0; db < 2; ++db)
#pragma unroll
        for (int e = 0; e < 16; ++e) oacc[db][e] = 0.0f;

    auto tile_body = [&](const u16* KsC, const u16* VtsC, const float* MsbC) {
        f32x16 sa;
#pragma unroll
        for (int p = 0; p < 4; ++p) {
            const f32x4 bb = *(const f32x4*)(MsbC + 32 * kb + 8 * p + hi4);
            sa[4*p+0] = bb[0]; sa[4*p+1] = bb[1]; sa[4*p+2] = bb[2]; sa[4*p+3] = bb[3];
        }
        __builtin_amdgcn_s_setprio(1);
#pragma unroll
        for (int kd = 0; kd < 4; ++kd) {
            const short8 kf = *(const short8*)(
                KsC + (size_t)(32 * kb + l5) * 64 + (((2 * kd + hi) ^ x7)) * 8);
            sa = __builtin_amdgcn_mfma_f32_32x32x16_bf16(kf, qfr[kd], sa, 0, 0, 0);
        }
        __builtin_amdgcn_s_setprio(0);

        float mx = fmaxf(
            fmaxf(fmaxf(fmaxf(sa[0], sa[1]),  fmaxf(sa[2], sa[3])),
                  fmaxf(fmaxf(sa[4], sa[5]),  fmaxf(sa[6], sa[7]))),
            fmaxf(fmaxf(fmaxf(sa[8], sa[9]),  fmaxf(sa[10], sa[11])),
                  fmaxf(fmaxf(sa[12], sa[13]), fmaxf(sa[14], sa[15]))));
        mx = fmaxf(mx, __shfl_xor(mx, 32));

        if (__any(mx > m_i + 8.0f)) {      // T13 threshold defer-rescale
            const float mnew = fmaxf(m_i, mx);
            const float a = EX2(m_i - mnew);
            m_i = mnew;
            l_i *= a;
            if (hi == 0) AlfR[l5] = a;
#pragma unroll
            for (int p = 0; p < 4; ++p) {
                const f32x4 a4 = *(const f32x4*)(&AlfR[8 * p + hi4]);
#pragma unroll
                for (int i = 0; i < 4; ++i) {
                    oacc[0][4*p+i] *= a4[i];
                    oacc[1][4*p+i] *= a4[i];
                }
            }
        }

        float pv[16];
#pragma unroll
        for (int r = 0; r < 16; ++r) pv[r] = EX2(sa[r] - m_i);
        float ss = ((pv[0]+pv[1]) + (pv[2]+pv[3])) + ((pv[4]+pv[5]) + (pv[6]+pv[7]))
                 + ((pv[8]+pv[9]) + (pv[10]+pv[11])) + ((pv[12]+pv[13]) + (pv[14]+pv[15]));
        ss += __shfl_xor(ss, 32);
        l_i += ss;

        unsigned W[8];
#pragma unroll
        for (int m = 0; m < 8; ++m) W[m] = cvt_pk_bf16(pv[2*m], pv[2*m+1]);

#pragma unroll
        for (int c1 = 0; c1 < 2; ++c1) {
            const unsigned X  = hi ? W[4*c1+0] : W[4*c1+2];
            const unsigned Y  = hi ? W[4*c1+1] : W[4*c1+3];
            const unsigned Xp = __shfl_xor((int)X, 32);
            const unsigned Yp = __shfl_xor((int)Y, 32);
            const unsigned w0 = hi ? Xp : W[4*c1+0];
            const unsigned w1 = hi ? Yp : W[4*c1+1];
            const unsigned w2 = hi ? W[4*c1+2] : Xp;
            const unsigned w3 = hi ? W[4*c1+3] : Yp;
            const short8 af = mk8(w0, w1, w2, w3);
            const int kcg = 2 * kb + c1;
            __builtin_amdgcn_s_setprio(1);
#pragma unroll
            for (int db = 0; db < 2; ++db) {
                const short8 vf = *(const short8*)(
                    VtsC + (size_t)(32 * db + l5) * 64 + (((2 * kcg + hi) ^ x7)) * 8);
                oacc[db] = __builtin_amdgcn_mfma_f32_32x32x16_bf16(af, vf, oacc[db], 0, 0, 0);
            }
            __builtin_amdgcn_s_setprio(0);
        }
    };

    // ---- flash loop: 32 super-tiles of 128 keys; 2 barriers each ----
    for (int it = 0; it < 32; ++it) {
        __syncthreads();
        *(uint4*)(KsA  + srow * 64 + sslot) = kregA;
        *(uint4*)(VtsA + srow * 64 + sslot) = vregA;
        *(uint4*)(KsB  + srow * 64 + sslot) = kregB;
        *(uint4*)(VtsB + srow * 64 + sslot) = vregB;
        if (t < 64) {
            Msb[t]      = (mregA == 0) ? -14427.0f : 0.0f;
            Msb[64 + t] = (mregB == 0) ? -14427.0f : 0.0f;
        }
        __syncthreads();
        if (it + 1 < 32) {
            const int kA = (it + 1) * 128, kB = kA + 64;
            kregA = *(const uint4*)(Kc + (size_t)(kA + srow) * 64 + scol8 * 8);
            vregA = *(const uint4*)(Vtc + (size_t)srow * L_ + kA + scol8 * 8);
            kregB = *(const uint4*)(Kc + (size_t)(kB + srow) * 64 + scol8 * 8);
            vregB = *(const uint4*)(Vtc + (size_t)srow * L_ + kB + scol8 * 8);
            if (t < 64) {
                mregA = mask[b * L_ + kA + t];
                mregB = mask[b * L_ + kB + t];
            }
        }
        tile_body(KsA, VtsA, Msb);
        tile_body(KsB, VtsB, Msb + 64);
    }

    // ---- merge the two key-streams (exact flash-combine), write output ----
    float* Op  = (float*)sm;
    float* Mp0 = (float*)(sm + 32768);
    float* Mp1 = Mp0 + 128;
    float* FA  = (float*)(sm + 33792);
    float* FB  = FA + 128;

    __syncthreads();
    if (wid >= 4) {
#pragma unroll
        for (int db = 0; db < 2; ++db) {
            const int d = 32 * db + l5;
#pragma unroll
            for (int p = 0; p < 4; ++p) {
                const int qb   = 32 * qg + 8 * p + hi4;
                const int slot = (qb >> 2) ^ l5;
                f32x4 v;
#pragma unroll
                for (int i = 0; i < 4; ++i) v[i] = oacc[db][4*p+i];
                *(f32x4*)(&Op[d * 128 + slot * 4]) = v;
            }
        }
        if (hi == 0) { Mp0[32 * qg + l5] = m_i; Mp1[32 * qg + l5] = l_i; }
    }
    __syncthreads();
    if (wid < 4) {
        const int q5 = 32 * qg + l5;
        const float mB = Mp0[q5], lB = Mp1[q5];
        const float mS = fmaxf(m_i, mB);
        const float aA = EX2(m_i - mS), aB = EX2(mB - mS);
        const float linv = 1.0f / (l_i * aA + lB * aB);
        if (hi == 0) { FA[q5] = aA * linv; FB[q5] = aB * linv; }
#pragma unroll
        for (int db = 0; db < 2; ++db) {
            const int d = 32 * db + l5;
            const int col = h * 64 + d;
#pragma unroll
            for (int p = 0; p < 4; ++p) {
                const int qb   = 32 * qg + 8 * p + hi4;
                const f32x4 fa = *(const f32x4*)(&FA[qb]);
                const f32x4 fb = *(const f32x4*)(&FB[qb]);
                const int slot = (qb >> 2) ^ l5;
                const f32x4 ob = *(const f32x4*)(&Op[d * 128 + slot * 4]);
#pragma unroll
                for (int i = 0; i < 4; ++i) {
                    const float val = oacc[db][4*p+i] * fa[i] + ob[i] * fb[i];
                    const size_t row = (size_t)b * L_ + q0 + qb + i;
                    if (Obf) Obf[row * 512 + col] = f2b(val);
                    else     O  [row * 512 + col] = val;
                }
            }
        }
    }
}

// ---------------------------------------------------------------------------
// Output projection v2, K-chunk 64 (verbatim R14).
// ---------------------------------------------------------------------------
template<bool BF>
__global__ __launch_bounds__(256) void outproj_v2_kernel(
    const u16* __restrict__ AO,
    const float* __restrict__ Wo, const u16* __restrict__ wobf,
    const float* __restrict__ bo,
    float* __restrict__ out)
{
    __shared__ __align__(16) unsigned char sm[18432];
    u16 (*As)[72] = (u16(*)[72])sm;
    u16 (*Bs)[72] = (u16(*)[72])(sm + 9216);

    const int t    = threadIdx.x;
    const int wid  = t >> 6, lane = t & 63;
    const int m15  = lane & 15, quad = lane >> 4;
    const int wm   = wid >> 1, wn = wid & 1;
    const int bm   = blockIdx.x * 64;
    const int n0   = blockIdx.y * 64;

    const int r0   = t >> 3;
    const int scol = (t & 7) * 8;

    const size_t ao0 = (size_t)(bm + r0) * 512 + scol;
    const size_t ao1 = ao0 + (size_t)32 * 512;
    const size_t bo0 = (size_t)(n0 + r0) * 512 + scol;
    const size_t bo1 = bo0 + (size_t)32 * 512;

    auto ldb = [&](size_t off, int k) -> uint4 {
        if constexpr (BF) return *(const uint4*)(wobf + off + k);
        else return pk8(*(const float4*)(Wo + off + k),
                        *(const float4*)(Wo + off + k + 4));
    };

    uint4 a0 = *(const uint4*)(AO + ao0), a1 = *(const uint4*)(AO + ao1);
    uint4 b0 = ldb(bo0, 0), b1 = ldb(bo1, 0);

    f32x4 acc[2][2] = {};

    for (int k0 = 0; k0 < 512; k0 += 64) {
        __syncthreads();
        *(uint4*)(&As[r0     ][scol]) = a0;
        *(uint4*)(&As[r0 + 32][scol]) = a1;
        *(uint4*)(&Bs[r0     ][scol]) = b0;
        *(uint4*)(&Bs[r0 + 32][scol]) = b1;
        __syncthreads();
        if (k0 + 64 < 512) {
            a0 = *(const uint4*)(AO + ao0 + k0 + 64);
            a1 = *(const uint4*)(AO + ao1 + k0 + 64);
            b0 = ldb(bo0, k0 + 64);
            b1 = ldb(bo1, k0 + 64);
        }

#pragma unroll
        for (int ks = 0; ks < 2; ++ks) {
            short8 afr[2], bfr[2];
#pragma unroll
            for (int mi = 0; mi < 2; ++mi)
                afr[mi] = *(const short8*)(&As[wm * 32 + mi * 16 + m15][ks * 32 + quad * 8]);
#pragma unroll
            for (int ni = 0; ni < 2; ++ni)
                bfr[ni] = *(const short8*)(&Bs[wn * 32 + ni * 16 + m15][ks * 32 + quad * 8]);
#pragma unroll
            for (int mi = 0; mi < 2; ++mi)
#pragma unroll
                for (int ni = 0; ni < 2; ++ni)
                    acc[mi][ni] = __builtin_amdgcn_mfma_f32_16x16x32_bf16(
                        afr[mi], bfr[ni], acc[mi][ni], 0, 0, 0);
        }
    }

#pragma unroll
    for (int mi = 0; mi < 2; ++mi)
#pragma unroll
        for (int ni = 0; ni < 2; ++ni) {
            const int col = n0 + wn * 32 + ni * 16 + m15;
            const float bv_ = bo[col];
#pragma unroll
            for (int r = 0; r < 4; ++r) {
                const int row = bm + wm * 32 + mi * 16 + quad * 4 + r;
                out[(size_t)row * 512 + col] = acc[mi][ni][r] + bv_;
            }
        }
}

// ---------------------------------------------------------------------------
// Fallback in-place fp32 output projection (unchanged).
// ---------------------------------------------------------------------------
__global__ __launch_bounds__(256) void outproj_inplace_kernel(
    float* __restrict__ AO,
    const float* __restrict__ Wo, const float* __restrict__ bo)
{
    __shared__ __align__(16) u16 As[32][520];
    __shared__ __align__(16) u16 Ws_[64][40];

    const int t    = threadIdx.x;
    const int wid  = t >> 6, lane = t & 63;
    const int m15  = lane & 15, quad = lane >> 4;
    const int wm   = wid >> 1, wn = wid & 1;
    const int bm   = blockIdx.x * 32;

#pragma unroll
    for (int it = 0; it < 8; ++it) {
        const int idx = t + it * 256;
        const int row = idx >> 6, c8 = (idx & 63) * 8;
        stage8f(&As[row][c8], AO + (size_t)(bm + row) * 512 + c8);
    }
    const int lrow = t >> 2;
    const int lcol = (t & 3) * 8;
    __syncthreads();

    for (int n0 = 0; n0 < 512; n0 += 64) {
        f32x4 acc[2] = {};
        for (int k0 = 0; k0 < 512; k0 += 32) {
            __syncthreads();
            stage8f(&Ws_[lrow][lcol], Wo + (size_t)(n0 + lrow) * 512 + k0 + lcol);
            __syncthreads();
            const short8 afr = *(const short8*)(&As[wm * 16 + m15][k0 + quad * 8]);
#pragma unroll
            for (int ni = 0; ni < 2; ++ni) {
                const short8 bfr = *(const short8*)(&Ws_[wn * 32 + ni * 16 + m15][quad * 8]);
                acc[ni] = __builtin_amdgcn_mfma_f32_16x16x32_bf16(afr, bfr, acc[ni], 0, 0, 0);
            }
        }
#pragma unroll
        for (int ni = 0; ni < 2; ++ni) {
            const int col = n0 + wn * 32 + ni * 16 + m15;
            const float bv_ = bo[col];
#pragma unroll
            for (int r = 0; r < 4; ++r) {
                const int row = bm + wm * 16 + quad * 4 + r;
                AO[(size_t)row * 512 + col] = acc[ni][r] + bv_;
            }
        }
    }
}

extern "C" void kernel_launch(void* const* d_in, const int* in_sizes, int n_in,
                              void* d_out, int out_size, void* d_ws, size_t ws_size,
                              hipStream_t stream) {
    const float* x    = (const float*)d_in[0];
    const int*   mask = (const int*)d_in[1];
    const float* Wq = (const float*)d_in[2]; const float* bq = (const float*)d_in[3];
    const float* Wk = (const float*)d_in[4]; const float* bk = (const float*)d_in[5];
    const float* Wv = (const float*)d_in[6]; const float* bv = (const float*)d_in[7];
    const float* Wo = (const float*)d_in[8]; const float* bo = (const float*)d_in[9];

    float* out = (float*)d_out;
    u16*   ws  = (u16*)d_ws;

    const size_t per_bh   = (size_t)2 * L_ * 64 * 2;
    const size_t kv_bytes = (size_t)BH_ * per_bh;           // 16 MiB
    const size_t ao_bytes = (size_t)M_ * 512 * 2;           // 8 MiB
    const size_t NX = (size_t)B_ * L_ * D_;
    const size_t NW = (size_t)D_ * D_;

    if (ws_size >= kv_bytes + ao_bytes) {
        u16* Kws  = ws;
        u16* Vws  = Kws + (size_t)BH_ * (L_ * 64);
        u16* AOws = ws + kv_bytes / 2;
        const bool can_prep = (size_t)out_size >= (NX + 3 * NW) * 2;
        u16* wobf = (ws_size >= kv_bytes + ao_bytes + NW * 2)
                        ? ws + (kv_bytes + ao_bytes) / 2 : nullptr;

        if (can_prep) {
            u16* xbf = (u16*)d_out;
            u16* wbf = xbf + NX;
            const int pgrid = (int)((NX + 4 * NW) / 2048);
            prep_kernel<<<pgrid, 256, 0, stream>>>(x, Wq, Wk, Wv, Wo,
                                                   xbf, wbf, wobf);
            kvproj_kernel<true><<<dim3(BH_, L_ / 64), 256, 0, stream>>>(
                x, xbf, Wk, bk, Wv, bv, wbf, Kws, Vws, 0);
            attn_kernel<true><<<dim3(L_ / 128, BH_), 512, 0, stream>>>(
                x, xbf, Wq, bq, wbf, Kws, Vws, mask, out, AOws, 0);
        } else {
            kvproj_kernel<false><<<dim3(BH_, L_ / 64), 256, 0, stream>>>(
                x, nullptr, Wk, bk, Wv, bv, nullptr, Kws, Vws, 0);
            attn_kernel<false><<<dim3(L_ / 128, BH_), 512, 0, stream>>>(
                x, nullptr, Wq, bq, nullptr, Kws, Vws, mask, out, AOws, 0);
        }
        if (wobf && can_prep)
            outproj_v2_kernel<true><<<dim3(M_ / 64, 8), 256, 0, stream>>>(
                AOws, Wo, wobf, bo, out);
        else
            outproj_v2_kernel<false><<<dim3(M_ / 64, 8), 256, 0, stream>>>(
                AOws, Wo, nullptr, bo, out);
    } else {
        int chunk = 16;
        while (chunk > 1 && (size_t)chunk * per_bh > ws_size) chunk >>= 1;
        u16* Kws = ws;
        u16* Vws = Kws + (size_t)chunk * (L_ * 64);
        for (int bh0 = 0; bh0 < BH_; bh0 += chunk) {
            kvproj_kernel<false><<<dim3(chunk, L_ / 64), 256, 0, stream>>>(
                x, nullptr, Wk, bk, Wv, bv, nullptr, Kws, Vws, bh0);
            attn_kernel<false><<<dim3(L_ / 128, chunk), 512, 0, stream>>>(
                x, nullptr, Wq, bq, nullptr, Kws, Vws, mask, out, nullptr, bh0);
        }
        outproj_inplace_kernel<<<dim3(M_ / 32), 256, 0, stream>>>(out, Wo, bo);
    }
}